// Round 7
// baseline (75.072 us; speedup 1.0000x reference)
//
#include <hip/hip_runtime.h>
#include <math.h>

#define MM 512
#define NN 1024
#define BB 64
#define SS 50
#define ETA 0.1f
#define NBLK 256
#define AGENT __HIP_MEMORY_SCOPE_AGENT

__device__ __forceinline__ float aload(const float* p) {
  return __hip_atomic_load(p, __ATOMIC_RELAXED, AGENT);
}
__device__ __forceinline__ void astore(float* p, float v) {
  __hip_atomic_store(p, v, __ATOMIC_RELAXED, AGENT);
}

// One-shot global barrier: slot must be 0 at kernel start (memset node).
// __syncthreads drains all the block's outstanding stores (compiler emits
// s_waitcnt vmcnt(0) before s_barrier); data already went through agent-scope
// atomics, so no L2 writeback is needed (this is what made cg::sync 33us).
__device__ __forceinline__ void gbar(unsigned* slot) {
  __syncthreads();
  if (threadIdx.x == 0) {
    asm volatile("s_waitcnt vmcnt(0) lgkmcnt(0)" ::: "memory");
    __hip_atomic_fetch_add(slot, 1u, __ATOMIC_RELAXED, AGENT);
    unsigned v;
    do {
      __builtin_amdgcn_s_sleep(2);
      v = __hip_atomic_load(slot, __ATOMIC_RELAXED, AGENT);
    } while (v < NBLK);
  }
  __syncthreads();
}

__global__ __launch_bounds__(512) void k_fused(
    const float* __restrict__ X,   // (N,B)
    const float* __restrict__ Y,   // (B,M)
    const float* __restrict__ A,   // (M,N)
    const float* __restrict__ W,   // (N)
    float* __restrict__ R,         // (M,B) ws, agent-atomic
    float* __restrict__ z_t,       // (B,N) ws, agent-atomic
    float* __restrict__ H1_t,      // (B,N) ws, agent-atomic
    float* __restrict__ c_part,    // (4,B,N) ws, agent-atomic
    unsigned* __restrict__ slots,  // 3 barrier counters, zeroed per launch
    float* __restrict__ out) {     // (N,B)
  const int bid = blockIdx.x;  // 0..255
  const int t = threadIdx.x;   // 0..511
  const int l = t & 63;
  const int w = t >> 6;

  __shared__ float p1[8][2][BB];
  __shared__ __align__(16) float Rs[2][MM];
  __shared__ float p2[2][4][128];
  __shared__ __align__(16) float zs[NN];
  __shared__ __align__(16) float2 zc_s[NN];
  __shared__ float mpart[8][NN];

  // ---------- Phase 1: R[m,b] = Y[b,m] - sum_n A[m,n]*X[n,b] ----------
  {
    const int m0 = bid * 2;
    const float* __restrict__ Xp = X + w * 128 * BB + l;
    const float* __restrict__ A0 = A + (size_t)m0 * NN + w * 128;
    const float* __restrict__ A1 = A0 + NN;
    float r0a = 0.f, r0b = 0.f, r1a = 0.f, r1b = 0.f;
    #pragma unroll 8
    for (int i = 0; i < 128; i += 4) {
      const float x0 = Xp[(i + 0) * BB];
      const float x1 = Xp[(i + 1) * BB];
      const float x2 = Xp[(i + 2) * BB];
      const float x3 = Xp[(i + 3) * BB];
      const float4 a0 = *reinterpret_cast<const float4*>(A0 + i);
      const float4 a1 = *reinterpret_cast<const float4*>(A1 + i);
      r0a = fmaf(a0.x, x0, fmaf(a0.y, x1, r0a));
      r0b = fmaf(a0.z, x2, fmaf(a0.w, x3, r0b));
      r1a = fmaf(a1.x, x0, fmaf(a1.y, x1, r1a));
      r1b = fmaf(a1.z, x2, fmaf(a1.w, x3, r1b));
    }
    p1[w][0][l] = r0a + r0b;
    p1[w][1][l] = r1a + r1b;
    __syncthreads();
    if (w < 2) {
      const float s =
          ((p1[0][w][l] + p1[1][w][l]) + (p1[2][w][l] + p1[3][w][l])) +
          ((p1[4][w][l] + p1[5][w][l]) + (p1[6][w][l] + p1[7][w][l]));
      astore(&R[(m0 + w) * BB + l], Y[l * MM + (m0 + w)] - s);
    }
  }
  gbar(slots + 0);

  // ---------- Phase 2: H1_t[b,n], z_t[b,n] ----------
  {
    const int nc = bid & 7;    // n-chunk of 128
    const int bp = bid >> 3;   // b-pair
    Rs[0][t] = aload(&R[t * BB + bp * 2 + 0]);
    Rs[1][t] = aload(&R[t * BB + bp * 2 + 1]);
    __syncthreads();
    const int b_l = w >> 2;    // 0..1
    const int mc = w & 3;      // m-chunk of 128
    const int n0 = nc * 128;
    const float2* __restrict__ A2 =
        reinterpret_cast<const float2*>(A) + (size_t)(mc * 128) * (NN / 2) + n0 / 2 + l;
    const float4* __restrict__ R4 =
        reinterpret_cast<const float4*>(Rs[b_l]) + mc * 32;
    float s0 = 0.f, s1 = 0.f, s2 = 0.f, s3 = 0.f;
    float u0 = 0.f, u1 = 0.f, u2 = 0.f, u3 = 0.f;
    #pragma unroll 2
    for (int i = 0; i < 128; i += 4) {
      const float4 r = R4[i >> 2];
      const float2 q0 = A2[(size_t)(i + 0) * (NN / 2)];
      const float2 q1 = A2[(size_t)(i + 1) * (NN / 2)];
      const float2 q2 = A2[(size_t)(i + 2) * (NN / 2)];
      const float2 q3 = A2[(size_t)(i + 3) * (NN / 2)];
      s0 = fmaf(q0.x, r.x, s0); u0 = fmaf(q0.y, r.x, u0);
      s1 = fmaf(q1.x, r.y, s1); u1 = fmaf(q1.y, r.y, u1);
      s2 = fmaf(q2.x, r.z, s2); u2 = fmaf(q2.y, r.z, u2);
      s3 = fmaf(q3.x, r.w, s3); u3 = fmaf(q3.y, r.w, u3);
    }
    p2[b_l][mc][l * 2 + 0] = (s0 + s1) + (s2 + s3);
    p2[b_l][mc][l * 2 + 1] = (u0 + u1) + (u2 + u3);
    __syncthreads();
    if (t < 256) {
      const int bl2 = t >> 7;
      const int nn = t & 127;
      const int bb = bp * 2 + bl2;
      const int n = n0 + nn;
      const float s = (p2[bl2][0][nn] + p2[bl2][1][nn]) +
                      (p2[bl2][2][nn] + p2[bl2][3][nn]);
      const float h = fmaf(ETA, s, X[n * BB + bb]);
      astore(&H1_t[bb * NN + n], h);
      astore(&z_t[bb * NN + n], fabsf(W[n] * h));
    }
  }
  gbar(slots + 1);

  // ---------- Phase 3: c_part[q][b][n], q-chunk of 256 j ----------
  {
    const int b = bid >> 2;
    const int q = bid & 3;
    zs[t] = aload(&z_t[b * NN + t]);
    zs[t + 512] = aload(&z_t[b * NN + t + 512]);
    __syncthreads();
    const float zn0 = zs[t];
    const float zn1 = zs[t + 512];
    float c0 = 0.f, c1 = 0.f;
    const float4* zq = reinterpret_cast<const float4*>(zs) + q * 64;
    #pragma unroll 4
    for (int i = 0; i < 64; ++i) {
      const float4 f = zq[i];
      c0 += (fabsf(zn0 - f.x) + fabsf(zn0 - f.y)) +
            (fabsf(zn0 - f.z) + fabsf(zn0 - f.w));
      c1 += (fabsf(zn1 - f.x) + fabsf(zn1 - f.y)) +
            (fabsf(zn1 - f.z) + fabsf(zn1 - f.w));
    }
    float* cp = c_part + q * (BB * NN) + b * NN;
    astore(cp + t, c0);
    astore(cp + t + 512, c1);
  }
  gbar(slots + 2);

  // ---------- Phase 4: softmax + mask + out (blocks 0..63) ----------
  if (bid < BB) {
    const int b = bid;
    const int BN = BB * NN;
    {
      const int i0 = b * NN + t;
      const int i1 = i0 + 512;
      const float cA = (aload(&c_part[i0]) + aload(&c_part[i0 + BN])) +
                       (aload(&c_part[i0 + 2 * BN]) + aload(&c_part[i0 + 3 * BN]));
      const float cB = (aload(&c_part[i1]) + aload(&c_part[i1 + BN])) +
                       (aload(&c_part[i1 + 2 * BN]) + aload(&c_part[i1 + 3 * BN]));
      zc_s[t] = make_float2(aload(&z_t[i0]), cA);
      zc_s[t + 512] = make_float2(aload(&z_t[i1]), cB);
    }
    __syncthreads();

    float zz[16], cc[16], mp[16];
    #pragma unroll
    for (int k = 0; k < 16; ++k) {
      const float2 v = zc_s[l + 64 * k];
      zz[k] = v.x;
      cc[k] = v.y;
      mp[k] = 0.f;
    }
    for (int s = w; s < SS; s += 8) {
      const float ks = (float)(NN + 1 - 2 * (s + 1));
      float lg[16];
      float mx = -INFINITY;
      #pragma unroll
      for (int k = 0; k < 16; ++k) {
        lg[k] = fmaf(ks, zz[k], -cc[k]);
        mx = fmaxf(mx, lg[k]);
      }
      #pragma unroll
      for (int off = 32; off > 0; off >>= 1)
        mx = fmaxf(mx, __shfl_xor(mx, off, 64));
      float sum = 0.f;
      #pragma unroll
      for (int k = 0; k < 16; ++k) {
        lg[k] = __expf(lg[k] - mx);
        sum += lg[k];
      }
      #pragma unroll
      for (int off = 32; off > 0; off >>= 1)
        sum += __shfl_xor(sum, off, 64);
      const float rs = 1.f / sum;
      #pragma unroll
      for (int k = 0; k < 16; ++k) mp[k] = fmaf(lg[k], rs, mp[k]);
    }
    #pragma unroll
    for (int k = 0; k < 16; ++k) mpart[w][l + 64 * k] = mp[k];
    __syncthreads();

    float m0 = 0.f, m1 = 0.f;
    #pragma unroll
    for (int u = 0; u < 8; ++u) {
      m0 += mpart[u][t];
      m1 += mpart[u][t + 512];
    }
    out[t * BB + b] = m0 * aload(&H1_t[b * NN + t]);
    out[(t + 512) * BB + b] = m1 * aload(&H1_t[b * NN + t + 512]);
  }
}

extern "C" void kernel_launch(void* const* d_in, const int* in_sizes, int n_in,
                              void* d_out, int out_size, void* d_ws, size_t ws_size,
                              hipStream_t stream) {
  const float* X = (const float*)d_in[0];  // (N,B)
  const float* Y = (const float*)d_in[1];  // (B,M)
  const float* A = (const float*)d_in[2];  // (M,N)
  const float* W = (const float*)d_in[3];  // (N,)
  float* out = (float*)d_out;              // (N,B)

  float* R = (float*)d_ws;                 // 32768 f
  float* z_t = R + MM * BB;                // 65536 f
  float* H1_t = z_t + NN * BB;             // 65536 f
  float* c_part = H1_t + NN * BB;          // 4*65536 f
  unsigned* slots = (unsigned*)(c_part + 4 * NN * BB);  // 3 u32

  hipMemsetAsync(slots, 0, 3 * sizeof(unsigned), stream);

  void* args[] = {(void*)&X, (void*)&Y, (void*)&A, (void*)&W,
                  (void*)&R, (void*)&z_t, (void*)&H1_t, (void*)&c_part,
                  (void*)&slots, (void*)&out};
  hipLaunchCooperativeKernel((void*)k_fused, dim3(NBLK), dim3(512), args, 0,
                             stream);
}

// Round 8
// 35.685 us; speedup vs baseline: 2.1037x; 2.1037x over previous
//
#include <hip/hip_runtime.h>
#include <math.h>

#define MM 512
#define NN 1024
#define BB 64
#define SS 50
#define ETA 0.1f

// K1: R_t[b][m] = Y[b,m] - sum_n A[m,n]*X[n,b]
// grid 256, block (64,8). Block owns 2 m-rows; wave w sums n-chunk w (128 n);
// 8-way LDS tree reduce; wave 0 writes float2 (m-pair) per batch.
__global__ __launch_bounds__(512) void k_r(const float* __restrict__ X,
                                           const float* __restrict__ Y,
                                           const float* __restrict__ A,
                                           float* __restrict__ R_t) {
  const int l = threadIdx.x;          // batch b
  const int w = threadIdx.y;          // n-chunk 0..7
  const int m0 = blockIdx.x * 2;
  __shared__ float part[8][2][BB];
  const float* __restrict__ Xp = X + w * 128 * BB + l;
  const float* __restrict__ A0 = A + (size_t)m0 * NN + w * 128;
  const float* __restrict__ A1 = A0 + NN;
  float r0a = 0.f, r0b = 0.f, r1a = 0.f, r1b = 0.f;
  #pragma unroll 8
  for (int i = 0; i < 128; i += 4) {
    const float x0 = Xp[(i + 0) * BB];
    const float x1 = Xp[(i + 1) * BB];
    const float x2 = Xp[(i + 2) * BB];
    const float x3 = Xp[(i + 3) * BB];
    const float4 a0 = *reinterpret_cast<const float4*>(A0 + i);
    const float4 a1 = *reinterpret_cast<const float4*>(A1 + i);
    r0a = fmaf(a0.x, x0, fmaf(a0.y, x1, r0a));
    r0b = fmaf(a0.z, x2, fmaf(a0.w, x3, r0b));
    r1a = fmaf(a1.x, x0, fmaf(a1.y, x1, r1a));
    r1b = fmaf(a1.z, x2, fmaf(a1.w, x3, r1b));
  }
  part[w][0][l] = r0a + r0b;
  part[w][1][l] = r1a + r1b;
  __syncthreads();
  if (w == 0) {
    const float s0 =
        ((part[0][0][l] + part[1][0][l]) + (part[2][0][l] + part[3][0][l])) +
        ((part[4][0][l] + part[5][0][l]) + (part[6][0][l] + part[7][0][l]));
    const float s1 =
        ((part[0][1][l] + part[1][1][l]) + (part[2][1][l] + part[3][1][l])) +
        ((part[4][1][l] + part[5][1][l]) + (part[6][1][l] + part[7][1][l]));
    const float2 y2 = *reinterpret_cast<const float2*>(Y + l * MM + m0);
    *reinterpret_cast<float2*>(R_t + l * MM + m0) =
        make_float2(y2.x - s0, y2.y - s1);
  }
}

// K2: H1_t[b,n] = X[n,b] + ETA*sum_m A[m,n]*R[m,b]; z_t[b,n] = |W[n]*H1|.
// grid 256 (8 nc x 32 bp), block (64,8). R columns staged in LDS (coalesced
// float4 from R_t rows), read back as wave-uniform ds_read_b128.
__global__ __launch_bounds__(512) void k_h1z(const float* __restrict__ X,
                                             const float* __restrict__ A,
                                             const float* __restrict__ R_t,
                                             const float* __restrict__ W,
                                             float* __restrict__ H1_t,
                                             float* __restrict__ z_t) {
  const int l = threadIdx.x;
  const int w = threadIdx.y;          // 0..7
  const int nc = blockIdx.x & 7;
  const int bp = blockIdx.x >> 3;     // 0..31
  const int t5 = w * 64 + l;          // 0..511
  __shared__ __align__(16) float Rs[2][MM];
  __shared__ float p2[2][4][128];

  if (t5 < 256) {
    const int row = t5 >> 7;          // 0..1
    const int idx = t5 & 127;         // 0..127 float4s
    reinterpret_cast<float4*>(Rs[row])[idx] =
        reinterpret_cast<const float4*>(R_t + (size_t)(bp * 2 + row) * MM)[idx];
  }
  __syncthreads();

  const int b_l = w >> 2;             // 0..1
  const int mc = w & 3;               // m-chunk of 128
  const int n0 = nc * 128;
  const float2* __restrict__ A2 =
      reinterpret_cast<const float2*>(A) + (size_t)(mc * 128) * (NN / 2) + n0 / 2 + l;
  const float4* __restrict__ R4 =
      reinterpret_cast<const float4*>(Rs[b_l]) + mc * 32;
  float s0 = 0.f, s1 = 0.f, s2 = 0.f, s3 = 0.f;
  float u0 = 0.f, u1 = 0.f, u2 = 0.f, u3 = 0.f;
  #pragma unroll 2
  for (int i = 0; i < 128; i += 4) {
    const float4 r = R4[i >> 2];
    const float2 q0 = A2[(size_t)(i + 0) * (NN / 2)];
    const float2 q1 = A2[(size_t)(i + 1) * (NN / 2)];
    const float2 q2 = A2[(size_t)(i + 2) * (NN / 2)];
    const float2 q3 = A2[(size_t)(i + 3) * (NN / 2)];
    s0 = fmaf(q0.x, r.x, s0); u0 = fmaf(q0.y, r.x, u0);
    s1 = fmaf(q1.x, r.y, s1); u1 = fmaf(q1.y, r.y, u1);
    s2 = fmaf(q2.x, r.z, s2); u2 = fmaf(q2.y, r.z, u2);
    s3 = fmaf(q3.x, r.w, s3); u3 = fmaf(q3.y, r.w, u3);
  }
  p2[b_l][mc][l * 2 + 0] = (s0 + s1) + (s2 + s3);
  p2[b_l][mc][l * 2 + 1] = (u0 + u1) + (u2 + u3);
  __syncthreads();
  if (t5 < 256) {
    const int bl2 = t5 >> 7;
    const int nn = t5 & 127;
    const int bb = bp * 2 + bl2;
    const int n = n0 + nn;
    const float s = (p2[bl2][0][nn] + p2[bl2][1][nn]) +
                    (p2[bl2][2][nn] + p2[bl2][3][nn]);
    const float h = fmaf(ETA, s, X[n * BB + bb]);
    H1_t[bb * NN + n] = h;
    z_t[bb * NN + n] = fabsf(W[n] * h);
  }
}

// K3: partial c. grid 256 (64 b x 4 j-chunks of 256), block 256.
// Thread owns 4 n; scans its j-chunk via broadcast float4 LDS reads.
// Output layout c_part[b][q][n] so K4's merge is 4 stride-NN loads.
__global__ __launch_bounds__(256) void k_c(const float* __restrict__ z_t,
                                           float* __restrict__ c_part) {
  const int b = blockIdx.x >> 2;
  const int q = blockIdx.x & 3;
  const int t = threadIdx.x;
  __shared__ __align__(16) float4 z4[NN / 4];
  z4[t] = reinterpret_cast<const float4*>(z_t + b * NN)[t];
  __syncthreads();
  const float* zs = reinterpret_cast<const float*>(z4);
  const float zn0 = zs[t];
  const float zn1 = zs[t + 256];
  const float zn2 = zs[t + 512];
  const float zn3 = zs[t + 768];
  float c0 = 0.f, c1 = 0.f, c2 = 0.f, c3 = 0.f;
  const float4* zq = z4 + q * 64;
  #pragma unroll 4
  for (int i = 0; i < 64; ++i) {
    const float4 f = zq[i];
    c0 += (fabsf(zn0 - f.x) + fabsf(zn0 - f.y)) + (fabsf(zn0 - f.z) + fabsf(zn0 - f.w));
    c1 += (fabsf(zn1 - f.x) + fabsf(zn1 - f.y)) + (fabsf(zn1 - f.z) + fabsf(zn1 - f.w));
    c2 += (fabsf(zn2 - f.x) + fabsf(zn2 - f.y)) + (fabsf(zn2 - f.z) + fabsf(zn2 - f.w));
    c3 += (fabsf(zn3 - f.x) + fabsf(zn3 - f.y)) + (fabsf(zn3 - f.z) + fabsf(zn3 - f.w));
  }
  float* cp = c_part + (size_t)(b * 4 + q) * NN;
  cp[t] = c0;
  cp[t + 256] = c1;
  cp[t + 512] = c2;
  cp[t + 768] = c3;
}

// K4: softmax + mask + out. grid 64, block 1024. Lane owns 16 interleaved n;
// zc float2 LDS (2-way, free), mpart scalar (conflict-free). Wave w handles
// s = w, w+16, w+32(, w+48). Fixed-order merges -> deterministic.
__global__ __launch_bounds__(1024) void k_sm(const float* __restrict__ z_t,
                                             const float* __restrict__ c_part,
                                             const float* __restrict__ H1_t,
                                             float* __restrict__ out) {
  const int b = blockIdx.x;
  const int t = threadIdx.x;
  __shared__ __align__(16) float2 zc_s[NN];
  __shared__ float mpart[16][NN];

  const float* __restrict__ cb = c_part + (size_t)b * 4 * NN;
  const float c = (cb[t] + cb[t + NN]) + (cb[t + 2 * NN] + cb[t + 3 * NN]);
  zc_s[t] = make_float2(z_t[b * NN + t], c);
  const float h = H1_t[b * NN + t];
  __syncthreads();

  const int w = t >> 6;
  const int lane = t & 63;
  float zz[16], cc[16], mp[16];
  #pragma unroll
  for (int k = 0; k < 16; ++k) {
    const float2 v = zc_s[lane + 64 * k];
    zz[k] = v.x;
    cc[k] = v.y;
    mp[k] = 0.f;
  }

  for (int s = w; s < SS; s += 16) {
    const float ks = (float)(NN + 1 - 2 * (s + 1));
    float lg[16];
    float mx = -INFINITY;
    #pragma unroll
    for (int k = 0; k < 16; ++k) {
      lg[k] = fmaf(ks, zz[k], -cc[k]);
      mx = fmaxf(mx, lg[k]);
    }
    #pragma unroll
    for (int off = 32; off > 0; off >>= 1)
      mx = fmaxf(mx, __shfl_xor(mx, off, 64));
    float sum = 0.f;
    #pragma unroll
    for (int k = 0; k < 16; ++k) {
      lg[k] = __expf(lg[k] - mx);
      sum += lg[k];
    }
    #pragma unroll
    for (int off = 32; off > 0; off >>= 1)
      sum += __shfl_xor(sum, off, 64);
    const float rs = 1.f / sum;
    #pragma unroll
    for (int k = 0; k < 16; ++k) mp[k] = fmaf(lg[k], rs, mp[k]);
  }
  #pragma unroll
  for (int k = 0; k < 16; ++k) mpart[w][lane + 64 * k] = mp[k];
  __syncthreads();

  float mask = 0.f;
  #pragma unroll
  for (int u = 0; u < 16; ++u) mask += mpart[u][t];
  out[t * BB + b] = mask * h;
}

extern "C" void kernel_launch(void* const* d_in, const int* in_sizes, int n_in,
                              void* d_out, int out_size, void* d_ws, size_t ws_size,
                              hipStream_t stream) {
  const float* X = (const float*)d_in[0];  // (N,B)
  const float* Y = (const float*)d_in[1];  // (B,M)
  const float* A = (const float*)d_in[2];  // (M,N)
  const float* W = (const float*)d_in[3];  // (N,)
  float* out = (float*)d_out;              // (N,B)

  float* R_t = (float*)d_ws;               // (B,M) = 32768 f
  float* z_t = R_t + BB * MM;              // (B,N) = 65536 f
  float* H1_t = z_t + BB * NN;             // (B,N) = 65536 f
  float* c_part = H1_t + BB * NN;          // (B,4,N) = 262144 f

  k_r   <<<dim3(MM / 2), dim3(64, 8), 0, stream>>>(X, Y, A, R_t);
  k_h1z <<<dim3(256), dim3(64, 8), 0, stream>>>(X, A, R_t, W, H1_t, z_t);
  k_c   <<<dim3(BB * 4), dim3(256), 0, stream>>>(z_t, c_part);
  k_sm  <<<dim3(BB), dim3(1024), 0, stream>>>(z_t, c_part, H1_t, out);
}